// Round 7
// baseline (85.823 us; speedup 1.0000x reference)
//
#include <hip/hip_runtime.h>
#include <stdint.h>

typedef unsigned short ushort_t;
typedef short short8 __attribute__((ext_vector_type(8)));
typedef float f32x4 __attribute__((ext_vector_type(4)));

#define CIN   64
#define COUT  128
#define BATCH 16
#define LPIX  1024               // 32*32
#define NTOT  (BATCH*LPIX)       // 16384
#define C2N   576                // CIN*9 features; c2 = f*64 + i (f-major)
#define PIXN  (BATCH*34*34)      // 18496 padded pixels
#define NSTEP2 72                // 8 basis slices (f=1..8) x 9 taps
#define KS    8                  // one basis slice per K-split block
#define PART_ELEMS (NTOT*COUT)   // 2,097,152
#define FEAT_BLOCKS (PIXN/4)                 // 4624
#define WPREP_BLOCKS (COUT*NSTEP2*64/256)    // 2304

// workspace layout (bytes)
#define FEAT_BYTES (PIXN*C2N*2)            // 21,307,392
#define W_OFF      FEAT_BYTES
#define W_BYTES    (COUT*NSTEP2*64*2)      // 1,179,648
#define BIAS_OFF   (W_OFF + W_BYTES)
#define PART_OFF   (BIAS_OFF + 512)
#define PART_BYTES (PART_ELEMS*4)          // 8,388,608
#define WS_NEED    ((size_t)PART_OFF + (size_t)(KS-1)*PART_BYTES)  // ~81 MB

__device__ __forceinline__ ushort_t to_bf16(float f) {
  union { float f; uint32_t u; } v; v.f = f;
  uint32_t r = (v.u + 0x7fffu + ((v.u >> 16) & 1u)) >> 16;
  return (ushort_t)r;
}

// H_0..H_7 (physicists') of x, plus silu(x) at [8]
__device__ __forceinline__ void basis9(float x, float* o) {
  float hm = 1.f, h = 2.f * x;
  o[0] = hm; o[1] = h;
#pragma unroll
  for (int n = 1; n < 7; ++n) {
    float nx = 2.f * x * h - 2.f * (float)n * hm;
    hm = h; h = nx;
    o[n + 1] = nx;
  }
  o[8] = x / (1.f + __expf(-x));
}

__device__ __forceinline__ void load16(const void* g, void* l) {
  __builtin_amdgcn_global_load_lds(
      (const __attribute__((address_space(1))) uint32_t*)g,
      (__attribute__((address_space(3))) uint32_t*)l, 16, 0, 0);
}

// -------- fused prep: feat (f=1..8 planes), W' (72 steps), f0-bias --------
// feat[pix(b,34,34)][f*64+i] bf16; plane f=0 never read (H_0==1 folded into
// bias). W' ushort idx = m*4608 + s*64 + swz(chunk,m)  with s = slice*9+kk,
// slice f = 1+s/9; 16B chunk (r>>3) xored with m&7 (storage-order writes).
// bias[o] = sum_{i,kk} wsp*cc[...,0]  (the H_0 contribution, exact f32).
__global__ void prep_kernel(const float* __restrict__ x, ushort_t* __restrict__ feat,
                            const float* __restrict__ wb, const float* __restrict__ wsp,
                            const float* __restrict__ cc, ushort_t* __restrict__ W,
                            float* __restrict__ bias) {
  const int t = threadIdx.x;
  if (blockIdx.x < FEAT_BLOCKS) {
    const int lane = t & 63;                      // = cin index i
    const int pg = blockIdx.x * 4 + (t >> 6);     // padded pixel id
    const int xx = pg % 34;
    const int rest = pg / 34;
    const int yy = rest % 34;
    const int bb = rest / 34;
    float v = 0.f;
    if (xx >= 1 && xx <= 32 && yy >= 1 && yy <= 32)
      v = x[((bb * CIN + lane) * 32 + (yy - 1)) * 32 + (xx - 1)];
    float o[9];
    basis9(v, o);
    ushort_t* dst = feat + (size_t)pg * C2N + lane;
#pragma unroll
    for (int f = 1; f < 9; ++f) dst[f * 64] = to_bf16(o[f]);  // skip f=0 plane
  } else if (blockIdx.x < FEAT_BLOCKS + WPREP_BLOCKS) {
    const int idx = (blockIdx.x - FEAT_BLOCKS) * 256 + t;     // storage index
    const int m = idx / (NSTEP2 * 64);
    const int pos = idx - m * (NSTEP2 * 64);
    const int s = pos >> 6;                                   // 0..71
    const int r = pos & 63;
    const int i = ((((r >> 3) & 7) ^ (m & 7)) << 3) | (r & 7);
    const int sf = 1 + s / 9;                                 // basis 1..8
    const int kk = s % 9;
    const int base = (i * COUT + m) * 9 + kk;
    const float val = (sf < 8) ? wsp[base] * cc[base * 8 + sf] : wb[base];
    W[idx] = to_bf16(val);
  } else {
    if (t < COUT) {
      float acc = 0.f;
      for (int i = 0; i < CIN; ++i)
#pragma unroll
        for (int kk = 0; kk < 9; ++kk) {
          const int base = (i * COUT + t) * 9 + kk;
          acc += wsp[base] * cc[base * 8];                    // H_0 term
        }
      bias[t] = acc;
    }
  }
}

// -------- GEMM: 128x256 tile, 8 waves, one basis-slice per block ----------
// block (nb, slice): basis f = slice+1, taps 0..8; halo (10 rows) staged
// once; A [m=128][k=64] double-buffered; 2 barriers/step, 9 steps.
__global__ __launch_bounds__(512, 4) void gemm_kernel(const ushort_t* __restrict__ feat,
                                                      const ushort_t* __restrict__ W,
                                                      const float* __restrict__ bias,
                                                      float* __restrict__ out,
                                                      float* __restrict__ part) {
  __shared__ ushort_t Ab[2][8192];     // 32 KB: [m=128][k=64], swizzled, dbuf
  __shared__ ushort_t Hb[2720 * 8];    // 43.5 KB: 340 px-rows x 64 feats
  const int t = threadIdx.x;
  const int lane = t & 63;
  const int wave = t >> 6;
  const int wm = wave >> 2, wn = wave & 3;   // 2M x 4N waves, 64x64 each

  // XCD-chunked remap, nb-major: each XCD gets 8 consecutive nb (2 images).
  const int logical = (blockIdx.x & 7) * 64 + (blockIdx.x >> 3);
  const int nb = logical >> 3;               // 0..63 (256-pixel N-tile)
  const int slice = logical & 7;             // basis f = slice+1

  const int b  = nb >> 2;                    // image
  const int y0 = (nb & 3) * 8;               // padded rows y0..y0+9
  const int pixbase = (b * 34 + y0) * 34;

  const char* Wb = (const char*)W;
  const char* Fb = (const char*)feat;

  f32x4 acc[4][4];
#pragma unroll
  for (int a = 0; a < 4; ++a)
#pragma unroll
    for (int c = 0; c < 4; ++c) acc[a][c] = (f32x4)0.f;

  // halo: 340 L (10 rows x 34 px) x 8 chunks; pix = pixbase + L.
  {
    const char* base = Fb + (size_t)pixbase * (C2N * 2) + (slice + 1) * 128;
#pragma unroll
    for (int it = 0; it < 6; ++it) {
      const int q = it * 512 + t;
      if (q < 2720) {
        const int L = q >> 3;
        const int sl = (q & 7) ^ (L & 7);
        load16(base + L * (C2N * 2) + (sl << 4), &Hb[q * 8]);
      }
    }
  }

  auto stageA = [&](int p, int j) {          // 2 DMA loads/thread
    const int s = slice * 9 + j;
#pragma unroll
    for (int q = 0; q < 2; ++q) {
      const int idx16 = q * 512 + t;
      const int m = idx16 >> 3, ccn = idx16 & 7;
      load16(Wb + m * (NSTEP2 * 64 * 2) + s * 128 + ccn * 16, &Ab[p][idx16 * 8]);
    }
  };

  auto compute = [&](int p, int j) {
    const int dy = j / 3, dx = j - dy * 3;
#pragma unroll
    for (int ks = 0; ks < 2; ++ks) {
      short8 av[4], bv[4];
      const int kslot = ks * 4 + (lane >> 4);
#pragma unroll
      for (int mf = 0; mf < 4; ++mf) {
        const int row = wm * 64 + mf * 16 + (lane & 15);
        av[mf] = *(const short8*)&Ab[p][row * 64 + ((kslot ^ (row & 7)) << 3)];
      }
#pragma unroll
      for (int nf = 0; nf < 4; ++nf) {
        const int nl = wn * 64 + nf * 16 + (lane & 15);   // 0..255 in tile
        const int L = ((nl >> 5) + dy) * 34 + (nl & 31) + dx;
        bv[nf] = *(const short8*)&Hb[L * 64 + ((kslot ^ (L & 7)) << 3)];
      }
#pragma unroll
      for (int mf = 0; mf < 4; ++mf)
#pragma unroll
        for (int nf = 0; nf < 4; ++nf)
          acc[mf][nf] = __builtin_amdgcn_mfma_f32_16x16x32_bf16(av[mf], bv[nf],
                                                                acc[mf][nf], 0, 0, 0);
    }
  };

  stageA(0, 0);
  __syncthreads();                           // halo + A(0) complete
  for (int j = 0; j < 9; ++j) {
    const int p = j & 1;
    if (j + 1 < 9) stageA(p ^ 1, j + 1);
    compute(p, j);
    __syncthreads();
  }

  float* dst = slice ? (part + (size_t)(slice - 1) * PART_ELEMS) : out;
#pragma unroll
  for (int mf = 0; mf < 4; ++mf)
#pragma unroll
    for (int rg = 0; rg < 4; ++rg) {
      const int m = wm * 64 + mf * 16 + (lane >> 4) * 4 + rg;
      const float bv = slice ? 0.f : bias[m];
#pragma unroll
      for (int nf = 0; nf < 4; ++nf) {
        const int n = nb * 256 + wn * 64 + nf * 16 + (lane & 15);
        const int bb = n >> 10, ll = n & 1023;
        dst[(bb * COUT + m) * LPIX + ll] = acc[mf][nf][rg] + bv;
      }
    }
}

template <int NP>
__global__ void add_kernel(float* __restrict__ out, const float* __restrict__ part) {
  const int i = (blockIdx.x * 256 + threadIdx.x) * 4;
  f32x4 a = *(const f32x4*)&out[i];
#pragma unroll
  for (int j = 0; j < NP; ++j)
    a += *(const f32x4*)&part[(size_t)j * PART_ELEMS + i];
  *(f32x4*)&out[i] = a;
}

// ---------------- fallback (only if ws too small): direct evaluation -----
__global__ void naive_kernel(const float* __restrict__ x, const float* __restrict__ wb,
                             const float* __restrict__ wsp, const float* __restrict__ cc,
                             float* __restrict__ out) {
  const int idx = blockIdx.x * 256 + threadIdx.x;
  if (idx >= BATCH * COUT * LPIX) return;
  const int l = idx & 1023, o = (idx >> 10) & 127, b = idx >> 17;
  const int h = l >> 5, w = l & 31;
  float acc = 0.f;
  for (int i = 0; i < CIN; ++i)
    for (int kk = 0; kk < 9; ++kk) {
      const int yy = h + kk / 3 - 1, xx = w + kk % 3 - 1;
      const float v = (yy >= 0 && yy < 32 && xx >= 0 && xx < 32)
                          ? x[((b * CIN + i) * 32 + yy) * 32 + xx] : 0.f;
      float ftr[9];
      basis9(v, ftr);
      const int base = (i * COUT + o) * 9 + kk;
      const float* cp = cc + base * 8;
      float dot = 0.f;
#pragma unroll
      for (int f = 0; f < 8; ++f) dot += cp[f] * ftr[f];
      acc += wsp[base] * dot + wb[base] * ftr[8];
    }
  out[idx] = acc;
}

extern "C" void kernel_launch(void* const* d_in, const int* in_sizes, int n_in,
                              void* d_out, int out_size, void* d_ws, size_t ws_size,
                              hipStream_t stream) {
  const float* x  = (const float*)d_in[0];
  const float* wb = (const float*)d_in[1];
  const float* wsp = (const float*)d_in[2];
  const float* cc = (const float*)d_in[3];
  float* out = (float*)d_out;

  if (ws_size < WS_NEED) {
    naive_kernel<<<(BATCH * COUT * LPIX + 255) / 256, 256, 0, stream>>>(x, wb, wsp, cc, out);
    return;
  }

  char* ws = (char*)d_ws;
  ushort_t* feat = (ushort_t*)ws;
  ushort_t* W    = (ushort_t*)(ws + W_OFF);
  float* bias    = (float*)(ws + BIAS_OFF);
  float* part    = (float*)(ws + PART_OFF);

  prep_kernel<<<FEAT_BLOCKS + WPREP_BLOCKS + 1, 256, 0, stream>>>(x, feat, wb, wsp, cc, W, bias);
  gemm_kernel<<<64 * KS, 512, 0, stream>>>(feat, W, bias, out, part);
  add_kernel<KS - 1><<<PART_ELEMS / 1024, 256, 0, stream>>>(out, part);
}

// Round 8
// 54.957 us; speedup vs baseline: 1.5616x; 1.5616x over previous
//
#include <hip/hip_runtime.h>
#include <stdint.h>

typedef unsigned short ushort_t;
typedef short short8 __attribute__((ext_vector_type(8)));
typedef float f32x4 __attribute__((ext_vector_type(4)));

#define CIN   64
#define COUT  128
#define BATCH 16
#define LPIX  1024               // 32*32
#define NTOT  (BATCH*LPIX)       // 16384
#define C2N   576                // CIN*9 features; c2 = f*64 + i (f-major)
#define PIXN  (BATCH*34*34)      // 18496 padded pixels
#define NSTEP2 72                // 8 basis slices (f=1..8) x 9 taps
#define KS    8                  // one basis slice per K-split block
#define PART_ELEMS (NTOT*COUT)   // 2,097,152
#define FEAT_BLOCKS (PIXN/4)                 // 4624
#define WPREP_BLOCKS (COUT*NSTEP2*64/256)    // 2304

// workspace layout (bytes)
#define FEAT_BYTES (PIXN*C2N*2)            // 21,307,392
#define W_OFF      FEAT_BYTES
#define W_BYTES    (COUT*NSTEP2*64*2)      // 1,179,648
#define BIAS_OFF   (W_OFF + W_BYTES)
#define PART_OFF   (BIAS_OFF + 512)
#define PART_BYTES (PART_ELEMS*4)          // 8,388,608
#define WS_NEED    ((size_t)PART_OFF + (size_t)(KS-1)*PART_BYTES)  // ~81 MB

__device__ __forceinline__ ushort_t to_bf16(float f) {
  union { float f; uint32_t u; } v; v.f = f;
  uint32_t r = (v.u + 0x7fffu + ((v.u >> 16) & 1u)) >> 16;
  return (ushort_t)r;
}

// H_0..H_7 (physicists') of x, plus silu(x) at [8]
__device__ __forceinline__ void basis9(float x, float* o) {
  float hm = 1.f, h = 2.f * x;
  o[0] = hm; o[1] = h;
#pragma unroll
  for (int n = 1; n < 7; ++n) {
    float nx = 2.f * x * h - 2.f * (float)n * hm;
    hm = h; h = nx;
    o[n + 1] = nx;
  }
  o[8] = x / (1.f + __expf(-x));
}

__device__ __forceinline__ void load16(const void* g, void* l) {
  __builtin_amdgcn_global_load_lds(
      (const __attribute__((address_space(1))) uint32_t*)g,
      (__attribute__((address_space(3))) uint32_t*)l, 16, 0, 0);
}

// -------- fused prep: feat (f=1..8 planes), W' (72 steps), f0-bias --------
// feat[pix(b,34,34)][f*64+i] bf16; plane f=0 never read (H_0==1 folded into
// bias). W' ushort idx = m*4608 + s*64 + swz(chunk,m)  with s = slice*9+kk,
// slice f = 1+s/9; 16B chunk (r>>3) xored with m&7 (storage-order writes).
// bias[o] = sum_{i,kk} wsp*cc[...,0]  — PARALLEL reduction (128 blocks),
// replacing R7's serial tail-block that cost ~47 us.
__global__ void prep_kernel(const float* __restrict__ x, ushort_t* __restrict__ feat,
                            const float* __restrict__ wb, const float* __restrict__ wsp,
                            const float* __restrict__ cc, ushort_t* __restrict__ W,
                            float* __restrict__ bias) {
  __shared__ float red[4];
  const int t = threadIdx.x;
  if (blockIdx.x < FEAT_BLOCKS) {
    const int lane = t & 63;                      // = cin index i
    const int pg = blockIdx.x * 4 + (t >> 6);     // padded pixel id
    const int xx = pg % 34;
    const int rest = pg / 34;
    const int yy = rest % 34;
    const int bb = rest / 34;
    float v = 0.f;
    if (xx >= 1 && xx <= 32 && yy >= 1 && yy <= 32)
      v = x[((bb * CIN + lane) * 32 + (yy - 1)) * 32 + (xx - 1)];
    float o[9];
    basis9(v, o);
    ushort_t* dst = feat + (size_t)pg * C2N + lane;
#pragma unroll
    for (int f = 1; f < 9; ++f) dst[f * 64] = to_bf16(o[f]);  // skip f=0 plane
  } else if (blockIdx.x < FEAT_BLOCKS + WPREP_BLOCKS) {
    const int idx = (blockIdx.x - FEAT_BLOCKS) * 256 + t;     // storage index
    const int m = idx / (NSTEP2 * 64);
    const int pos = idx - m * (NSTEP2 * 64);
    const int s = pos >> 6;                                   // 0..71
    const int r = pos & 63;
    const int i = ((((r >> 3) & 7) ^ (m & 7)) << 3) | (r & 7);
    const int sf = 1 + s / 9;                                 // basis 1..8
    const int kk = s % 9;
    const int base = (i * COUT + m) * 9 + kk;
    const float val = (sf < 8) ? wsp[base] * cc[base * 8 + sf] : wb[base];
    W[idx] = to_bf16(val);
  } else {
    // bias[m]: parallel over 256 threads, wave-reduce, LDS combine.
    const int m = blockIdx.x - (FEAT_BLOCKS + WPREP_BLOCKS);  // 0..127
    float p = 0.f;
    for (int e = t; e < CIN * 9; e += 256) {
      const int i = e / 9, kk = e - i * 9;
      const int base = (i * COUT + m) * 9 + kk;
      p += wsp[base] * cc[base * 8];                          // H_0 term
    }
#pragma unroll
    for (int off = 32; off > 0; off >>= 1) p += __shfl_down(p, off, 64);
    if ((t & 63) == 0) red[t >> 6] = p;
    __syncthreads();
    if (t == 0) bias[m] = red[0] + red[1] + red[2] + red[3];
  }
}

// -------- GEMM: 128x256 tile, 8 waves, one basis-slice per block ----------
// block (nb, slice): basis f = slice+1, taps 0..8; halo (10 rows) staged
// once; A [m=128][k=64] double-buffered; 2 barriers/step, 9 steps.
__global__ __launch_bounds__(512, 4) void gemm_kernel(const ushort_t* __restrict__ feat,
                                                      const ushort_t* __restrict__ W,
                                                      const float* __restrict__ bias,
                                                      float* __restrict__ out,
                                                      float* __restrict__ part) {
  __shared__ ushort_t Ab[2][8192];     // 32 KB: [m=128][k=64], swizzled, dbuf
  __shared__ ushort_t Hb[2720 * 8];    // 43.5 KB: 340 px-rows x 64 feats
  const int t = threadIdx.x;
  const int lane = t & 63;
  const int wave = t >> 6;
  const int wm = wave >> 2, wn = wave & 3;   // 2M x 4N waves, 64x64 each

  // XCD-chunked remap, nb-major: each XCD gets 8 consecutive nb (2 images).
  const int logical = (blockIdx.x & 7) * 64 + (blockIdx.x >> 3);
  const int nb = logical >> 3;               // 0..63 (256-pixel N-tile)
  const int slice = logical & 7;             // basis f = slice+1

  const int b  = nb >> 2;                    // image
  const int y0 = (nb & 3) * 8;               // padded rows y0..y0+9
  const int pixbase = (b * 34 + y0) * 34;

  const char* Wb = (const char*)W;
  const char* Fb = (const char*)feat;

  f32x4 acc[4][4];
#pragma unroll
  for (int a = 0; a < 4; ++a)
#pragma unroll
    for (int c = 0; c < 4; ++c) acc[a][c] = (f32x4)0.f;

  // halo: 340 L (10 rows x 34 px) x 8 chunks; pix = pixbase + L.
  {
    const char* base = Fb + (size_t)pixbase * (C2N * 2) + (slice + 1) * 128;
#pragma unroll
    for (int it = 0; it < 6; ++it) {
      const int q = it * 512 + t;
      if (q < 2720) {
        const int L = q >> 3;
        const int sl = (q & 7) ^ (L & 7);
        load16(base + L * (C2N * 2) + (sl << 4), &Hb[q * 8]);
      }
    }
  }

  auto stageA = [&](int p, int j) {          // 2 DMA loads/thread
    const int s = slice * 9 + j;
#pragma unroll
    for (int q = 0; q < 2; ++q) {
      const int idx16 = q * 512 + t;
      const int m = idx16 >> 3, ccn = idx16 & 7;
      load16(Wb + m * (NSTEP2 * 64 * 2) + s * 128 + ccn * 16, &Ab[p][idx16 * 8]);
    }
  };

  auto compute = [&](int p, int j) {
    const int dy = j / 3, dx = j - dy * 3;
#pragma unroll
    for (int ks = 0; ks < 2; ++ks) {
      short8 av[4], bv[4];
      const int kslot = ks * 4 + (lane >> 4);
#pragma unroll
      for (int mf = 0; mf < 4; ++mf) {
        const int row = wm * 64 + mf * 16 + (lane & 15);
        av[mf] = *(const short8*)&Ab[p][row * 64 + ((kslot ^ (row & 7)) << 3)];
      }
#pragma unroll
      for (int nf = 0; nf < 4; ++nf) {
        const int nl = wn * 64 + nf * 16 + (lane & 15);   // 0..255 in tile
        const int L = ((nl >> 5) + dy) * 34 + (nl & 31) + dx;
        bv[nf] = *(const short8*)&Hb[L * 64 + ((kslot ^ (L & 7)) << 3)];
      }
#pragma unroll
      for (int mf = 0; mf < 4; ++mf)
#pragma unroll
        for (int nf = 0; nf < 4; ++nf)
          acc[mf][nf] = __builtin_amdgcn_mfma_f32_16x16x32_bf16(av[mf], bv[nf],
                                                                acc[mf][nf], 0, 0, 0);
    }
  };

  stageA(0, 0);
  __syncthreads();                           // halo + A(0) complete
  for (int j = 0; j < 9; ++j) {
    const int p = j & 1;
    if (j + 1 < 9) stageA(p ^ 1, j + 1);
    compute(p, j);
    __syncthreads();
  }

  float* dst = slice ? (part + (size_t)(slice - 1) * PART_ELEMS) : out;
#pragma unroll
  for (int mf = 0; mf < 4; ++mf)
#pragma unroll
    for (int rg = 0; rg < 4; ++rg) {
      const int m = wm * 64 + mf * 16 + (lane >> 4) * 4 + rg;
      const float bv = slice ? 0.f : bias[m];
#pragma unroll
      for (int nf = 0; nf < 4; ++nf) {
        const int n = nb * 256 + wn * 64 + nf * 16 + (lane & 15);
        const int bb = n >> 10, ll = n & 1023;
        dst[(bb * COUT + m) * LPIX + ll] = acc[mf][nf][rg] + bv;
      }
    }
}

template <int NP>
__global__ void add_kernel(float* __restrict__ out, const float* __restrict__ part) {
  const int i = (blockIdx.x * 256 + threadIdx.x) * 4;
  f32x4 a = *(const f32x4*)&out[i];
#pragma unroll
  for (int j = 0; j < NP; ++j)
    a += *(const f32x4*)&part[(size_t)j * PART_ELEMS + i];
  *(f32x4*)&out[i] = a;
}

// ---------------- fallback (only if ws too small): direct evaluation -----
__global__ void naive_kernel(const float* __restrict__ x, const float* __restrict__ wb,
                             const float* __restrict__ wsp, const float* __restrict__ cc,
                             float* __restrict__ out) {
  const int idx = blockIdx.x * 256 + threadIdx.x;
  if (idx >= BATCH * COUT * LPIX) return;
  const int l = idx & 1023, o = (idx >> 10) & 127, b = idx >> 17;
  const int h = l >> 5, w = l & 31;
  float acc = 0.f;
  for (int i = 0; i < CIN; ++i)
    for (int kk = 0; kk < 9; ++kk) {
      const int yy = h + kk / 3 - 1, xx = w + kk % 3 - 1;
      const float v = (yy >= 0 && yy < 32 && xx >= 0 && xx < 32)
                          ? x[((b * CIN + i) * 32 + yy) * 32 + xx] : 0.f;
      float ftr[9];
      basis9(v, ftr);
      const int base = (i * COUT + o) * 9 + kk;
      const float* cp = cc + base * 8;
      float dot = 0.f;
#pragma unroll
      for (int f = 0; f < 8; ++f) dot += cp[f] * ftr[f];
      acc += wsp[base] * dot + wb[base] * ftr[8];
    }
  out[idx] = acc;
}

extern "C" void kernel_launch(void* const* d_in, const int* in_sizes, int n_in,
                              void* d_out, int out_size, void* d_ws, size_t ws_size,
                              hipStream_t stream) {
  const float* x  = (const float*)d_in[0];
  const float* wb = (const float*)d_in[1];
  const float* wsp = (const float*)d_in[2];
  const float* cc = (const float*)d_in[3];
  float* out = (float*)d_out;

  if (ws_size < WS_NEED) {
    naive_kernel<<<(BATCH * COUT * LPIX + 255) / 256, 256, 0, stream>>>(x, wb, wsp, cc, out);
    return;
  }

  char* ws = (char*)d_ws;
  ushort_t* feat = (ushort_t*)ws;
  ushort_t* W    = (ushort_t*)(ws + W_OFF);
  float* bias    = (float*)(ws + BIAS_OFF);
  float* part    = (float*)(ws + PART_OFF);

  prep_kernel<<<FEAT_BLOCKS + WPREP_BLOCKS + COUT, 256, 0, stream>>>(x, feat, wb, wsp, cc, W, bias);
  gemm_kernel<<<64 * KS, 512, 0, stream>>>(feat, W, bias, out, part);
  add_kernel<KS - 1><<<PART_ELEMS / 1024, 256, 0, stream>>>(out, part);
}

// Round 9
// 48.892 us; speedup vs baseline: 1.7554x; 1.1241x over previous
//
#include <hip/hip_runtime.h>
#include <stdint.h>

typedef unsigned short ushort_t;
typedef short short8 __attribute__((ext_vector_type(8)));
typedef float f32x4 __attribute__((ext_vector_type(4)));

#define CIN   64
#define COUT  128
#define BATCH 16
#define LPIX  1024               // 32*32
#define NTOT  (BATCH*LPIX)       // 16384
#define C2N   576                // CIN*9 features; c2 = f*64 + i (f-major)
#define PIXN  (BATCH*34*34)      // 18496 padded pixels
#define NSTEP2 72                // 8 basis slices (f=1..8) x 9 taps
#define KS    4                  // K-split: 18 steps (2 slices) per block
#define PART_ELEMS (NTOT*COUT)   // 2,097,152
#define FEAT_BLOCKS (PIXN/4)                 // 4624
#define WPREP_BLOCKS (COUT*NSTEP2*64/256)    // 2304

// workspace layout (bytes)
#define FEAT_BYTES (PIXN*C2N*2)            // 21,307,392
#define W_OFF      FEAT_BYTES
#define W_BYTES    (COUT*NSTEP2*64*2)      // 1,179,648
#define BIAS_OFF   (W_OFF + W_BYTES)
#define PART_OFF   (BIAS_OFF + 512)
#define PART_BYTES (PART_ELEMS*4)          // 8,388,608
#define WS_NEED    ((size_t)PART_OFF + (size_t)(KS-1)*PART_BYTES)  // ~48 MB

__device__ __forceinline__ ushort_t to_bf16(float f) {
  union { float f; uint32_t u; } v; v.f = f;
  uint32_t r = (v.u + 0x7fffu + ((v.u >> 16) & 1u)) >> 16;
  return (ushort_t)r;
}

// H_0..H_7 (physicists') of x, plus silu(x) at [8]
__device__ __forceinline__ void basis9(float x, float* o) {
  float hm = 1.f, h = 2.f * x;
  o[0] = hm; o[1] = h;
#pragma unroll
  for (int n = 1; n < 7; ++n) {
    float nx = 2.f * x * h - 2.f * (float)n * hm;
    hm = h; h = nx;
    o[n + 1] = nx;
  }
  o[8] = x / (1.f + __expf(-x));
}

__device__ __forceinline__ void load16(const void* g, void* l) {
  __builtin_amdgcn_global_load_lds(
      (const __attribute__((address_space(1))) uint32_t*)g,
      (__attribute__((address_space(3))) uint32_t*)l, 16, 0, 0);
}

// -------- fused prep (R8-verified): feat f=1..8, W' 72 steps, f0-bias -----
// feat[pix(b,34,34)][f*64+i] bf16; f=0 plane never read (H_0==1 -> bias).
// W' ushort idx = m*4608 + s*64 + r, s = slice*9+kk (basis f=1+s/9); within
// each 64-k group, 16B chunk (r>>3) holds logical chunk (r>>3)^(m&7).
// bias[o] = sum_{i,kk} wsp*cc[...,0]  (parallel, 128 blocks).
__global__ void prep_kernel(const float* __restrict__ x, ushort_t* __restrict__ feat,
                            const float* __restrict__ wb, const float* __restrict__ wsp,
                            const float* __restrict__ cc, ushort_t* __restrict__ W,
                            float* __restrict__ bias) {
  __shared__ float red[4];
  const int t = threadIdx.x;
  if (blockIdx.x < FEAT_BLOCKS) {
    const int lane = t & 63;                      // = cin index i
    const int pg = blockIdx.x * 4 + (t >> 6);     // padded pixel id
    const int xx = pg % 34;
    const int rest = pg / 34;
    const int yy = rest % 34;
    const int bb = rest / 34;
    float v = 0.f;
    if (xx >= 1 && xx <= 32 && yy >= 1 && yy <= 32)
      v = x[((bb * CIN + lane) * 32 + (yy - 1)) * 32 + (xx - 1)];
    float o[9];
    basis9(v, o);
    ushort_t* dst = feat + (size_t)pg * C2N + lane;
#pragma unroll
    for (int f = 1; f < 9; ++f) dst[f * 64] = to_bf16(o[f]);  // skip f=0 plane
  } else if (blockIdx.x < FEAT_BLOCKS + WPREP_BLOCKS) {
    const int idx = (blockIdx.x - FEAT_BLOCKS) * 256 + t;     // storage index
    const int m = idx / (NSTEP2 * 64);
    const int pos = idx - m * (NSTEP2 * 64);
    const int s = pos >> 6;                                   // 0..71
    const int r = pos & 63;
    const int i = ((((r >> 3) & 7) ^ (m & 7)) << 3) | (r & 7);
    const int sf = 1 + s / 9;                                 // basis 1..8
    const int kk = s % 9;
    const int base = (i * COUT + m) * 9 + kk;
    const float val = (sf < 8) ? wsp[base] * cc[base * 8 + sf] : wb[base];
    W[idx] = to_bf16(val);
  } else {
    const int m = blockIdx.x - (FEAT_BLOCKS + WPREP_BLOCKS);  // 0..127
    float p = 0.f;
    for (int e = t; e < CIN * 9; e += 256) {
      const int i = e / 9, kk = e - i * 9;
      const int base = (i * COUT + m) * 9 + kk;
      p += wsp[base] * cc[base * 8];                          // H_0 term
    }
#pragma unroll
    for (int off = 32; off > 0; off >>= 1) p += __shfl_down(p, off, 64);
    if ((t & 63) == 0) red[t >> 6] = p;
    __syncthreads();
    if (t == 0) bias[m] = red[0] + red[1] + red[2] + red[3];
  }
}

// -------- GEMM: 64x256 tile, M-split x K-split, 2 blocks/CU ---------------
// block (nb, mt, ksplit): M rows mt*64..+63, N pixels nb*256..+255,
// steps s in [ksplit*18, ksplit*18+18) — 2 basis slices x 9 taps.
// Halo (10 rows x 34 px x 64 feats) staged once per slice; A [64][64]
// double-buffered; R6-verified 2-barrier step schedule.
__global__ __launch_bounds__(256, 2) void gemm_kernel(const ushort_t* __restrict__ feat,
                                                      const ushort_t* __restrict__ W,
                                                      const float* __restrict__ bias,
                                                      float* __restrict__ out,
                                                      float* __restrict__ part) {
  __shared__ ushort_t Ab[2][4096];     // 16 KB: [m=64][k=64], swizzled, dbuf
  __shared__ ushort_t Hb[2720 * 8];    // 43.5 KB: 340 px-rows x 64 feats
  const int t = threadIdx.x;
  const int lane = t & 63;
  const int wn = t >> 6;               // 4 N-split waves, each 64x64

  // XCD-chunked remap: XCD x gets logical [x*64, x*64+64) = 8 nb-tiles.
  const int logical = (blockIdx.x & 7) * 64 + (blockIdx.x >> 3);
  const int nb = logical >> 3;               // 0..63 (256-pixel N-tile)
  const int rem = logical & 7;
  const int mt = rem >> 2;                   // 0..1 (64-row M-tile)
  const int ksplit = rem & 3;                // 0..3
  const int lo = ksplit * 18, hi = lo + 18;

  const int b  = nb >> 2;                    // image
  const int y0 = (nb & 3) * 8;               // padded rows y0..y0+9
  const int pixbase = (b * 34 + y0) * 34;

  const char* Wb = (const char*)W + mt * 64 * (NSTEP2 * 64 * 2);
  const char* Fb = (const char*)feat;

  f32x4 acc[4][4];
#pragma unroll
  for (int a = 0; a < 4; ++a)
#pragma unroll
    for (int c = 0; c < 4; ++c) acc[a][c] = (f32x4)0.f;

  auto stage_halo = [&](int c2s) {           // slice c2s = s/9, basis f=c2s+1
    const char* base = Fb + (size_t)pixbase * (C2N * 2) + (c2s + 1) * 128;
#pragma unroll
    for (int it = 0; it < 11; ++it) {
      const int q = it * 256 + t;            // 2720 chunks: 340 L x 8
      if (q < 2720) {
        const int L = q >> 3;
        const int sl = (q & 7) ^ (L & 7);
        load16(base + L * (C2N * 2) + (sl << 4), &Hb[q * 8]);
      }
    }
  };

  auto stageA = [&](int p, int s) {          // 2 DMA loads/thread
#pragma unroll
    for (int q = 0; q < 2; ++q) {
      const int idx16 = q * 256 + t;         // 512 chunks: 64 rows x 8
      const int m = idx16 >> 3, ccn = idx16 & 7;
      load16(Wb + m * (NSTEP2 * 64 * 2) + s * 128 + ccn * 16, &Ab[p][idx16 * 8]);
    }
  };

  auto compute = [&](int p, int j) {         // tap j = s%9
    const int dy = j / 3, dx = j - dy * 3;
#pragma unroll
    for (int ks = 0; ks < 2; ++ks) {
      short8 av[4], bv[4];
      const int kslot = ks * 4 + (lane >> 4);
#pragma unroll
      for (int mf = 0; mf < 4; ++mf) {
        const int row = mf * 16 + (lane & 15);
        av[mf] = *(const short8*)&Ab[p][row * 64 + ((kslot ^ (row & 7)) << 3)];
      }
#pragma unroll
      for (int nf = 0; nf < 4; ++nf) {
        const int nl = wn * 64 + nf * 16 + (lane & 15);   // 0..255 in tile
        const int L = ((nl >> 5) + dy) * 34 + (nl & 31) + dx;
        bv[nf] = *(const short8*)&Hb[L * 64 + ((kslot ^ (L & 7)) << 3)];
      }
#pragma unroll
      for (int mf = 0; mf < 4; ++mf)
#pragma unroll
        for (int nf = 0; nf < 4; ++nf)
          acc[mf][nf] = __builtin_amdgcn_mfma_f32_16x16x32_bf16(av[mf], bv[nf],
                                                                acc[mf][nf], 0, 0, 0);
    }
  };

  stage_halo(lo / 9);
  stageA(0, lo);
  __syncthreads();                           // halo + A(lo) complete
  for (int s = lo; s < hi; ++s) {
    const int p = (s - lo) & 1;
    if (s + 1 < hi) stageA(p ^ 1, s + 1);
    compute(p, s % 9);
    __syncthreads();
    if (s + 1 < hi && ((s + 1) % 9) == 0) {  // slice boundary: restage halo
      stage_halo((s + 1) / 9);
      __syncthreads();
    }
  }

  float* dst = ksplit ? (part + (size_t)(ksplit - 1) * PART_ELEMS) : out;
#pragma unroll
  for (int mf = 0; mf < 4; ++mf)
#pragma unroll
    for (int rg = 0; rg < 4; ++rg) {
      const int m = mt * 64 + mf * 16 + (lane >> 4) * 4 + rg;
      const float bv = ksplit ? 0.f : bias[m];
#pragma unroll
      for (int nf = 0; nf < 4; ++nf) {
        const int n = nb * 256 + wn * 64 + nf * 16 + (lane & 15);
        const int bb = n >> 10, ll = n & 1023;
        dst[(bb * COUT + m) * LPIX + ll] = acc[mf][nf][rg] + bv;
      }
    }
}

template <int NP>
__global__ void add_kernel(float* __restrict__ out, const float* __restrict__ part) {
  const int i = (blockIdx.x * 256 + threadIdx.x) * 4;
  f32x4 a = *(const f32x4*)&out[i];
#pragma unroll
  for (int j = 0; j < NP; ++j)
    a += *(const f32x4*)&part[(size_t)j * PART_ELEMS + i];
  *(f32x4*)&out[i] = a;
}

// ---------------- fallback (only if ws too small): direct evaluation -----
__global__ void naive_kernel(const float* __restrict__ x, const float* __restrict__ wb,
                             const float* __restrict__ wsp, const float* __restrict__ cc,
                             float* __restrict__ out) {
  const int idx = blockIdx.x * 256 + threadIdx.x;
  if (idx >= BATCH * COUT * LPIX) return;
  const int l = idx & 1023, o = (idx >> 10) & 127, b = idx >> 17;
  const int h = l >> 5, w = l & 31;
  float acc = 0.f;
  for (int i = 0; i < CIN; ++i)
    for (int kk = 0; kk < 9; ++kk) {
      const int yy = h + kk / 3 - 1, xx = w + kk % 3 - 1;
      const float v = (yy >= 0 && yy < 32 && xx >= 0 && xx < 32)
                          ? x[((b * CIN + i) * 32 + yy) * 32 + xx] : 0.f;
      float ftr[9];
      basis9(v, ftr);
      const int base = (i * COUT + o) * 9 + kk;
      const float* cp = cc + base * 8;
      float dot = 0.f;
#pragma unroll
      for (int f = 0; f < 8; ++f) dot += cp[f] * ftr[f];
      acc += wsp[base] * dot + wb[base] * ftr[8];
    }
  out[idx] = acc;
}

extern "C" void kernel_launch(void* const* d_in, const int* in_sizes, int n_in,
                              void* d_out, int out_size, void* d_ws, size_t ws_size,
                              hipStream_t stream) {
  const float* x  = (const float*)d_in[0];
  const float* wb = (const float*)d_in[1];
  const float* wsp = (const float*)d_in[2];
  const float* cc = (const float*)d_in[3];
  float* out = (float*)d_out;

  if (ws_size < WS_NEED) {
    naive_kernel<<<(BATCH * COUT * LPIX + 255) / 256, 256, 0, stream>>>(x, wb, wsp, cc, out);
    return;
  }

  char* ws = (char*)d_ws;
  ushort_t* feat = (ushort_t*)ws;
  ushort_t* W    = (ushort_t*)(ws + W_OFF);
  float* bias    = (float*)(ws + BIAS_OFF);
  float* part    = (float*)(ws + PART_OFF);

  prep_kernel<<<FEAT_BLOCKS + WPREP_BLOCKS + COUT, 256, 0, stream>>>(x, feat, wb, wsp, cc, W, bias);
  gemm_kernel<<<64 * 2 * KS, 256, 0, stream>>>(feat, W, bias, out, part);
  add_kernel<KS - 1><<<PART_ELEMS / 1024, 256, 0, stream>>>(out, part);
}

// Round 10
// 45.880 us; speedup vs baseline: 1.8706x; 1.0656x over previous
//
#include <hip/hip_runtime.h>
#include <stdint.h>

typedef unsigned short ushort_t;
typedef short short8 __attribute__((ext_vector_type(8)));
typedef float f32x4 __attribute__((ext_vector_type(4)));

#define CIN   64
#define COUT  128
#define BATCH 16
#define LPIX  1024               // 32*32
#define NTOT  (BATCH*LPIX)       // 16384
#define C2N   576                // CIN*9 features; c2 = f*64 + i (f-major)
#define PIXN  (BATCH*34*34)      // 18496 padded pixels
#define NSTEP2 72                // 8 basis slices (f=1..8) x 9 taps
#define KS    4                  // K-split: 18 steps (2 slices) per block
#define PART_ELEMS (NTOT*COUT)   // 2,097,152
#define FEAT_BLOCKS (PIXN/4)                 // 4624
#define WPREP_BLOCKS (COUT*NSTEP2*64/256)    // 2304

// workspace layout (bytes)
#define FEAT_BYTES (PIXN*C2N*2)            // 21,307,392
#define W_OFF      FEAT_BYTES
#define W_BYTES    (COUT*NSTEP2*64*2)      // 1,179,648
#define BIAS_OFF   (W_OFF + W_BYTES)
#define PART_OFF   (BIAS_OFF + 512)
#define PART_BYTES (PART_ELEMS*4)          // 8,388,608
#define WS_NEED    ((size_t)PART_OFF + (size_t)(KS-1)*PART_BYTES)  // ~48 MB

#define WAITVM(n) asm volatile("s_waitcnt vmcnt(" #n ")" ::: "memory")
#define BAR() __builtin_amdgcn_s_barrier()

__device__ __forceinline__ ushort_t to_bf16(float f) {
  union { float f; uint32_t u; } v; v.f = f;
  uint32_t r = (v.u + 0x7fffu + ((v.u >> 16) & 1u)) >> 16;
  return (ushort_t)r;
}

// H_0..H_7 (physicists') of x, plus silu(x) at [8]
__device__ __forceinline__ void basis9(float x, float* o) {
  float hm = 1.f, h = 2.f * x;
  o[0] = hm; o[1] = h;
#pragma unroll
  for (int n = 1; n < 7; ++n) {
    float nx = 2.f * x * h - 2.f * (float)n * hm;
    hm = h; h = nx;
    o[n + 1] = nx;
  }
  o[8] = x / (1.f + __expf(-x));
}

__device__ __forceinline__ void load16(const void* g, void* l) {
  __builtin_amdgcn_global_load_lds(
      (const __attribute__((address_space(1))) uint32_t*)g,
      (__attribute__((address_space(3))) uint32_t*)l, 16, 0, 0);
}

// -------- fused prep (R8/R9-verified): feat f=1..8, W' 72 steps, bias -----
__global__ void prep_kernel(const float* __restrict__ x, ushort_t* __restrict__ feat,
                            const float* __restrict__ wb, const float* __restrict__ wsp,
                            const float* __restrict__ cc, ushort_t* __restrict__ W,
                            float* __restrict__ bias) {
  __shared__ float red[4];
  const int t = threadIdx.x;
  if (blockIdx.x < FEAT_BLOCKS) {
    const int lane = t & 63;                      // = cin index i
    const int pg = blockIdx.x * 4 + (t >> 6);     // padded pixel id
    const int xx = pg % 34;
    const int rest = pg / 34;
    const int yy = rest % 34;
    const int bb = rest / 34;
    float v = 0.f;
    if (xx >= 1 && xx <= 32 && yy >= 1 && yy <= 32)
      v = x[((bb * CIN + lane) * 32 + (yy - 1)) * 32 + (xx - 1)];
    float o[9];
    basis9(v, o);
    ushort_t* dst = feat + (size_t)pg * C2N + lane;
#pragma unroll
    for (int f = 1; f < 9; ++f) dst[f * 64] = to_bf16(o[f]);  // skip f=0 plane
  } else if (blockIdx.x < FEAT_BLOCKS + WPREP_BLOCKS) {
    const int idx = (blockIdx.x - FEAT_BLOCKS) * 256 + t;     // storage index
    const int m = idx / (NSTEP2 * 64);
    const int pos = idx - m * (NSTEP2 * 64);
    const int s = pos >> 6;                                   // 0..71
    const int r = pos & 63;
    const int i = ((((r >> 3) & 7) ^ (m & 7)) << 3) | (r & 7);
    const int sf = 1 + s / 9;                                 // basis 1..8
    const int kk = s % 9;
    const int base = (i * COUT + m) * 9 + kk;
    const float val = (sf < 8) ? wsp[base] * cc[base * 8 + sf] : wb[base];
    W[idx] = to_bf16(val);
  } else {
    const int m = blockIdx.x - (FEAT_BLOCKS + WPREP_BLOCKS);  // 0..127
    float p = 0.f;
    for (int e = t; e < CIN * 9; e += 256) {
      const int i = e / 9, kk = e - i * 9;
      const int base = (i * COUT + m) * 9 + kk;
      p += wsp[base] * cc[base * 8];                          // H_0 term
    }
#pragma unroll
    for (int off = 32; off > 0; off >>= 1) p += __shfl_down(p, off, 64);
    if ((t & 63) == 0) red[t >> 6] = p;
    __syncthreads();
    if (t == 0) bias[m] = red[0] + red[1] + red[2] + red[3];
  }
}

// -------- GEMM: 64x256 tile, counted-vmcnt pipeline (T4) ------------------
// A 4-deep buffered, prefetch depth 2; one raw s_barrier per step; vmcnt
// never 0 in steady state (4 = two 2-load A batches in flight across the
// barrier). Halo staged once per slice with a single exposed drain.
__global__ __launch_bounds__(256, 2) void gemm_kernel(const ushort_t* __restrict__ feat,
                                                      const ushort_t* __restrict__ W,
                                                      const float* __restrict__ bias,
                                                      float* __restrict__ out,
                                                      float* __restrict__ part) {
  __shared__ ushort_t Ab[4][4096];     // 32 KB: [m=64][k=64], swizzled, 4-deep
  __shared__ ushort_t Hb[2720 * 8];    // 43.5 KB: 340 px-rows x 64 feats
  const int t = threadIdx.x;
  const int lane = t & 63;
  const int wn = t >> 6;               // 4 N-split waves, each 64x64

  // XCD-chunked remap: XCD x gets logical [x*64, x*64+64) = 8 nb-tiles.
  const int logical = (blockIdx.x & 7) * 64 + (blockIdx.x >> 3);
  const int nb = logical >> 3;               // 0..63 (256-pixel N-tile)
  const int rem = logical & 7;
  const int mt = rem >> 2;                   // 0..1 (64-row M-tile)
  const int ksplit = rem & 3;                // 0..3
  const int lo = ksplit * 18;                // slices 2*ksplit, 2*ksplit+1

  const int b  = nb >> 2;                    // image
  const int y0 = (nb & 3) * 8;               // padded rows y0..y0+9
  const int pixbase = (b * 34 + y0) * 34;

  const char* Wb = (const char*)W + mt * 64 * (NSTEP2 * 64 * 2);
  const char* Fb = (const char*)feat;

  f32x4 acc[4][4];
#pragma unroll
  for (int a = 0; a < 4; ++a)
#pragma unroll
    for (int c = 0; c < 4; ++c) acc[a][c] = (f32x4)0.f;

  auto stage_halo = [&](int c2s) {           // basis f = c2s+1
    const char* base = Fb + (size_t)pixbase * (C2N * 2) + (c2s + 1) * 128;
#pragma unroll
    for (int it = 0; it < 11; ++it) {
      const int q = it * 256 + t;            // 2720 chunks: 340 L x 8
      if (q < 2720) {
        const int L = q >> 3;
        const int sl = (q & 7) ^ (L & 7);
        load16(base + L * (C2N * 2) + (sl << 4), &Hb[q * 8]);
      }
    }
  };

  auto stageA = [&](int p, int s) {          // 2 DMA loads/thread, always
#pragma unroll
    for (int q = 0; q < 2; ++q) {
      const int idx16 = q * 256 + t;         // 512 chunks: 64 rows x 8
      const int m = idx16 >> 3, ccn = idx16 & 7;
      load16(Wb + m * (NSTEP2 * 64 * 2) + s * 128 + ccn * 16, &Ab[p][idx16 * 8]);
    }
  };

  auto compute = [&](int p, int j) {         // tap j (compile-time)
    const int dy = j / 3, dx = j - dy * 3;
#pragma unroll
    for (int ks = 0; ks < 2; ++ks) {
      short8 av[4], bv[4];
      const int kslot = ks * 4 + (lane >> 4);
#pragma unroll
      for (int mf = 0; mf < 4; ++mf) {
        const int row = mf * 16 + (lane & 15);
        av[mf] = *(const short8*)&Ab[p][row * 64 + ((kslot ^ (row & 7)) << 3)];
      }
#pragma unroll
      for (int nf = 0; nf < 4; ++nf) {
        const int nl = wn * 64 + nf * 16 + (lane & 15);   // 0..255 in tile
        const int L = ((nl >> 5) + dy) * 34 + (nl & 31) + dx;
        bv[nf] = *(const short8*)&Hb[L * 64 + ((kslot ^ (L & 7)) << 3)];
      }
#pragma unroll
      for (int mf = 0; mf < 4; ++mf)
#pragma unroll
        for (int nf = 0; nf < 4; ++nf)
          acc[mf][nf] = __builtin_amdgcn_mfma_f32_16x16x32_bf16(av[mf], bv[nf],
                                                                acc[mf][nf], 0, 0, 0);
    }
  };

  // Per-step: issue A(j+2), wait to N outstanding (N counts exactly the
  // younger A batches; uniform per-thread), barrier (no drain), compute.
#define GSTEP(j, N)                                         \
  {                                                         \
    if ((j) + 2 < 18) stageA(((j) + 2) & 3, lo + (j) + 2);  \
    WAITVM(N);                                              \
    BAR();                                                  \
    compute((j) & 3, (j) % 9);                              \
  }

  // prologue: halo(slice0) oldest, then A(lo), A(lo+1)
  stage_halo(2 * ksplit);
  stageA(0, lo);
  stageA(1, lo + 1);

  GSTEP(0, 4);  GSTEP(1, 4);  GSTEP(2, 4);  GSTEP(3, 4);  GSTEP(4, 4);
  GSTEP(5, 4);  GSTEP(6, 4);  GSTEP(7, 4);  GSTEP(8, 4);

  BAR();                          // all waves done reading halo(slice0)
  stage_halo(2 * ksplit + 1);     // issue H2 (drained by GSTEP(9)'s vmcnt(2))

  GSTEP(9, 2);  GSTEP(10, 4); GSTEP(11, 4); GSTEP(12, 4); GSTEP(13, 4);
  GSTEP(14, 4); GSTEP(15, 4); GSTEP(16, 2); GSTEP(17, 0);
#undef GSTEP

  float* dst = ksplit ? (part + (size_t)(ksplit - 1) * PART_ELEMS) : out;
#pragma unroll
  for (int mf = 0; mf < 4; ++mf)
#pragma unroll
    for (int rg = 0; rg < 4; ++rg) {
      const int m = mt * 64 + mf * 16 + (lane >> 4) * 4 + rg;
      const float bv = ksplit ? 0.f : bias[m];
#pragma unroll
      for (int nf = 0; nf < 4; ++nf) {
        const int n = nb * 256 + wn * 64 + nf * 16 + (lane & 15);
        const int bb = n >> 10, ll = n & 1023;
        dst[(bb * COUT + m) * LPIX + ll] = acc[mf][nf][rg] + bv;
      }
    }
}

template <int NP>
__global__ void add_kernel(float* __restrict__ out, const float* __restrict__ part) {
  const int i = (blockIdx.x * 256 + threadIdx.x) * 4;
  f32x4 a = *(const f32x4*)&out[i];
#pragma unroll
  for (int j = 0; j < NP; ++j)
    a += *(const f32x4*)&part[(size_t)j * PART_ELEMS + i];
  *(f32x4*)&out[i] = a;
}

// ---------------- fallback (only if ws too small): direct evaluation -----
__global__ void naive_kernel(const float* __restrict__ x, const float* __restrict__ wb,
                             const float* __restrict__ wsp, const float* __restrict__ cc,
                             float* __restrict__ out) {
  const int idx = blockIdx.x * 256 + threadIdx.x;
  if (idx >= BATCH * COUT * LPIX) return;
  const int l = idx & 1023, o = (idx >> 10) & 127, b = idx >> 17;
  const int h = l >> 5, w = l & 31;
  float acc = 0.f;
  for (int i = 0; i < CIN; ++i)
    for (int kk = 0; kk < 9; ++kk) {
      const int yy = h + kk / 3 - 1, xx = w + kk % 3 - 1;
      const float v = (yy >= 0 && yy < 32 && xx >= 0 && xx < 32)
                          ? x[((b * CIN + i) * 32 + yy) * 32 + xx] : 0.f;
      float ftr[9];
      basis9(v, ftr);
      const int base = (i * COUT + o) * 9 + kk;
      const float* cp = cc + base * 8;
      float dot = 0.f;
#pragma unroll
      for (int f = 0; f < 8; ++f) dot += cp[f] * ftr[f];
      acc += wsp[base] * dot + wb[base] * ftr[8];
    }
  out[idx] = acc;
}

extern "C" void kernel_launch(void* const* d_in, const int* in_sizes, int n_in,
                              void* d_out, int out_size, void* d_ws, size_t ws_size,
                              hipStream_t stream) {
  const float* x  = (const float*)d_in[0];
  const float* wb = (const float*)d_in[1];
  const float* wsp = (const float*)d_in[2];
  const float* cc = (const float*)d_in[3];
  float* out = (float*)d_out;

  if (ws_size < WS_NEED) {
    naive_kernel<<<(BATCH * COUT * LPIX + 255) / 256, 256, 0, stream>>>(x, wb, wsp, cc, out);
    return;
  }

  char* ws = (char*)d_ws;
  ushort_t* feat = (ushort_t*)ws;
  ushort_t* W    = (ushort_t*)(ws + W_OFF);
  float* bias    = (float*)(ws + BIAS_OFF);
  float* part    = (float*)(ws + PART_OFF);

  prep_kernel<<<FEAT_BLOCKS + WPREP_BLOCKS + COUT, 256, 0, stream>>>(x, feat, wb, wsp, cc, W, bias);
  gemm_kernel<<<64 * 2 * KS, 256, 0, stream>>>(feat, W, bias, out, part);
  add_kernel<KS - 1><<<PART_ELEMS / 1024, 256, 0, stream>>>(out, part);
}

// Round 11
// 45.549 us; speedup vs baseline: 1.8842x; 1.0073x over previous
//
#include <hip/hip_runtime.h>
#include <stdint.h>

typedef unsigned short ushort_t;
typedef short short8 __attribute__((ext_vector_type(8)));
typedef float f32x4 __attribute__((ext_vector_type(4)));

#define CIN   64
#define COUT  128
#define BATCH 16
#define LPIX  1024               // 32*32
#define NTOT  (BATCH*LPIX)       // 16384
#define C2N   576                // CIN*9 features; c2 = f*64 + i (f-major)
#define PIXN  (BATCH*34*34)      // 18496 padded pixels
#define NSTEP2 72                // 8 basis slices (f=1..8) x 9 taps
#define KS    4                  // K-split: 18 steps (2 slices) per block
#define PART_ELEMS (NTOT*COUT)   // 2,097,152
#define FEAT_BLOCKS (PIXN/4)     // 4624
#define WPREP_BLOCKS 32          // 4 m x 64 i per block

// workspace layout (bytes)
#define FEAT_BYTES (PIXN*C2N*2)            // 21,307,392
#define W_OFF      FEAT_BYTES
#define W_BYTES    (COUT*NSTEP2*64*2)      // 1,179,648
#define BIAS_OFF   (W_OFF + W_BYTES)
#define PART_OFF   (BIAS_OFF + 512)
#define PART_BYTES (PART_ELEMS*2)          // bf16 partials: 4,194,304
#define WS_NEED    ((size_t)PART_OFF + (size_t)(KS-1)*PART_BYTES)

#define WAITVM(n) asm volatile("s_waitcnt vmcnt(" #n ")" ::: "memory")
#define BAR() __builtin_amdgcn_s_barrier()

__device__ __forceinline__ ushort_t to_bf16(float f) {
  union { float f; uint32_t u; } v; v.f = f;
  uint32_t r = (v.u + 0x7fffu + ((v.u >> 16) & 1u)) >> 16;
  return (ushort_t)r;
}
__device__ __forceinline__ float from_bf16(ushort_t u) {
  union { uint32_t u; float f; } v; v.u = ((uint32_t)u) << 16;
  return v.f;
}

// H_0..H_7 (physicists') of x, plus silu(x) at [8]
__device__ __forceinline__ void basis9(float x, float* o) {
  float hm = 1.f, h = 2.f * x;
  o[0] = hm; o[1] = h;
#pragma unroll
  for (int n = 1; n < 7; ++n) {
    float nx = 2.f * x * h - 2.f * (float)n * hm;
    hm = h; h = nx;
    o[n + 1] = nx;
  }
  o[8] = x / (1.f + __expf(-x));
}

__device__ __forceinline__ void load16(const void* g, void* l) {
  __builtin_amdgcn_global_load_lds(
      (const __attribute__((address_space(1))) uint32_t*)g,
      (__attribute__((address_space(3))) uint32_t*)l, 16, 0, 0);
}

// -------- fused prep: feat f=1..8 (coalesced), W' + bias (coalesced) ------
// feat[pix(b,34,34)][f*64+i] bf16. W' idx = m*4608 + s*64 + r; storage
// chunk (r>>3) holds logical chunk (r>>3)^(m&7); s = (f-1)*9 + kk.
// W-prep: thread=(i,m) reads wsp/cc CONTIGUOUSLY, LDS-transposes, writes W
// in coalesced 128B rows. bias[m] = sum_{i,kk} wsp*cc[...,0] (H_0 fold).
__global__ void prep_kernel(const float* __restrict__ x, ushort_t* __restrict__ feat,
                            const float* __restrict__ wb, const float* __restrict__ wsp,
                            const float* __restrict__ cc, ushort_t* __restrict__ W,
                            float* __restrict__ bias) {
  __shared__ ushort_t wl[4][NSTEP2 * 64 + 16];
  __shared__ float bl[16];
  const int t = threadIdx.x;
  if (blockIdx.x < FEAT_BLOCKS) {
    const int lane = t & 63;                      // = cin index i
    const int pg = blockIdx.x * 4 + (t >> 6);     // padded pixel id
    const int xx = pg % 34;
    const int rest = pg / 34;
    const int yy = rest % 34;
    const int bb = rest / 34;
    float v = 0.f;
    if (xx >= 1 && xx <= 32 && yy >= 1 && yy <= 32)
      v = x[((bb * CIN + lane) * 32 + (yy - 1)) * 32 + (xx - 1)];
    float o[9];
    basis9(v, o);
    ushort_t* dst = feat + (size_t)pg * C2N + lane;
#pragma unroll
    for (int f = 1; f < 9; ++f) dst[f * 64] = to_bf16(o[f]);  // skip f=0 plane
  } else {
    const int mg = blockIdx.x - FEAT_BLOCKS;      // 0..31
    const int i = t >> 2;                         // 0..63
    const int mq = t & 3;
    const int m = mg * 4 + mq;
    const int base = (i * COUT + m) * 9;
    const int r = ((((i >> 3) & 7) ^ (m & 7)) << 3) | (i & 7);
    float h0 = 0.f;
#pragma unroll
    for (int kk = 0; kk < 9; ++kk) {
      const float ws_ = wsp[base + kk];
      const float wbv = wb[base + kk];
      const float* cp = cc + (size_t)(base + kk) * 8;
      h0 += ws_ * cp[0];
#pragma unroll
      for (int sf = 1; sf <= 8; ++sf) {
        const float val = (sf < 8) ? ws_ * cp[sf] : wbv;
        wl[mq][((sf - 1) * 9 + kk) * 64 + r] = to_bf16(val);
      }
    }
#pragma unroll
    for (int off = 4; off < 64; off <<= 1) h0 += __shfl_down(h0, off, 64);
    if ((t & 63) < 4) bl[(t >> 6) * 4 + (t & 3)] = h0;
    __syncthreads();
    if (t < 4) bias[mg * 4 + t] = bl[t] + bl[4 + t] + bl[8 + t] + bl[12 + t];
    // write out: 288 rows (4 mq x 72 s) x 32 dwords, fully coalesced
#pragma unroll 4
    for (int jj = 0; jj < 36; ++jj) {
      const int flat = jj * 256 + t;
      const int row = flat >> 5, col = flat & 31;
      const int mq2 = row / NSTEP2, s2 = row - mq2 * NSTEP2;
      const uint32_t v = *(const uint32_t*)&wl[mq2][s2 * 64 + col * 2];
      *(uint32_t*)&W[(size_t)(mg * 4 + mq2) * (NSTEP2 * 64) + s2 * 64 + col * 2] = v;
    }
  }
}

// -------- GEMM: 64x256 tile, counted-vmcnt pipeline (T4) + setprio (T5) ---
__global__ __launch_bounds__(256, 2) void gemm_kernel(const ushort_t* __restrict__ feat,
                                                      const ushort_t* __restrict__ W,
                                                      const float* __restrict__ bias,
                                                      float* __restrict__ out,
                                                      ushort_t* __restrict__ part) {
  __shared__ ushort_t Ab[4][4096];     // 32 KB: [m=64][k=64], swizzled, 4-deep
  __shared__ ushort_t Hb[2720 * 8];    // 43.5 KB: 340 px-rows x 64 feats
  const int t = threadIdx.x;
  const int lane = t & 63;
  const int wn = t >> 6;               // 4 N-split waves, each 64x64

  const int logical = (blockIdx.x & 7) * 64 + (blockIdx.x >> 3);
  const int nb = logical >> 3;               // 0..63 (256-pixel N-tile)
  const int rem = logical & 7;
  const int mt = rem >> 2;                   // 0..1 (64-row M-tile)
  const int ksplit = rem & 3;                // 0..3
  const int lo = ksplit * 18;                // slices 2*ksplit, 2*ksplit+1

  const int b  = nb >> 2;                    // image
  const int y0 = (nb & 3) * 8;               // padded rows y0..y0+9
  const int pixbase = (b * 34 + y0) * 34;

  const char* Wb = (const char*)W + mt * 64 * (NSTEP2 * 64 * 2);
  const char* Fb = (const char*)feat;

  f32x4 acc[4][4];
#pragma unroll
  for (int a = 0; a < 4; ++a)
#pragma unroll
    for (int c = 0; c < 4; ++c) acc[a][c] = (f32x4)0.f;

  auto stage_halo = [&](int c2s) {           // basis f = c2s+1
    const char* base = Fb + (size_t)pixbase * (C2N * 2) + (c2s + 1) * 128;
#pragma unroll
    for (int it = 0; it < 11; ++it) {
      const int q = it * 256 + t;            // 2720 chunks: 340 L x 8
      if (q < 2720) {
        const int L = q >> 3;
        const int sl = (q & 7) ^ (L & 7);
        load16(base + L * (C2N * 2) + (sl << 4), &Hb[q * 8]);
      }
    }
  };

  auto stageA = [&](int p, int s) {          // 2 DMA loads/thread, always
#pragma unroll
    for (int q = 0; q < 2; ++q) {
      const int idx16 = q * 256 + t;         // 512 chunks: 64 rows x 8
      const int m = idx16 >> 3, ccn = idx16 & 7;
      load16(Wb + m * (NSTEP2 * 64 * 2) + s * 128 + ccn * 16, &Ab[p][idx16 * 8]);
    }
  };

  auto compute = [&](int p, int j) {         // tap j (compile-time)
    const int dy = j / 3, dx = j - dy * 3;
#pragma unroll
    for (int ks = 0; ks < 2; ++ks) {
      short8 av[4], bv[4];
      const int kslot = ks * 4 + (lane >> 4);
#pragma unroll
      for (int mf = 0; mf < 4; ++mf) {
        const int row = mf * 16 + (lane & 15);
        av[mf] = *(const short8*)&Ab[p][row * 64 + ((kslot ^ (row & 7)) << 3)];
      }
#pragma unroll
      for (int nf = 0; nf < 4; ++nf) {
        const int nl = wn * 64 + nf * 16 + (lane & 15);   // 0..255 in tile
        const int L = ((nl >> 5) + dy) * 34 + (nl & 31) + dx;
        bv[nf] = *(const short8*)&Hb[L * 64 + ((kslot ^ (L & 7)) << 3)];
      }
      __builtin_amdgcn_s_setprio(1);
#pragma unroll
      for (int mf = 0; mf < 4; ++mf)
#pragma unroll
        for (int nf = 0; nf < 4; ++nf)
          acc[mf][nf] = __builtin_amdgcn_mfma_f32_16x16x32_bf16(av[mf], bv[nf],
                                                                acc[mf][nf], 0, 0, 0);
      __builtin_amdgcn_s_setprio(0);
    }
  };

#define GSTEP(j, N)                                         \
  {                                                         \
    if ((j) + 2 < 18) stageA(((j) + 2) & 3, lo + (j) + 2);  \
    WAITVM(N);                                              \
    BAR();                                                  \
    compute((j) & 3, (j) % 9);                              \
  }

  stage_halo(2 * ksplit);
  stageA(0, lo);
  stageA(1, lo + 1);

  GSTEP(0, 4);  GSTEP(1, 4);  GSTEP(2, 4);  GSTEP(3, 4);  GSTEP(4, 4);
  GSTEP(5, 4);  GSTEP(6, 4);  GSTEP(7, 4);  GSTEP(8, 4);

  BAR();                          // all waves done reading halo(slice0)
  stage_halo(2 * ksplit + 1);     // drained by GSTEP(9)'s vmcnt(2)

  GSTEP(9, 2);  GSTEP(10, 4); GSTEP(11, 4); GSTEP(12, 4); GSTEP(13, 4);
  GSTEP(14, 4); GSTEP(15, 4); GSTEP(16, 2); GSTEP(17, 0);
#undef GSTEP

  if (ksplit) {
    ushort_t* dst = part + (size_t)(ksplit - 1) * PART_ELEMS;
#pragma unroll
    for (int mf = 0; mf < 4; ++mf)
#pragma unroll
      for (int rg = 0; rg < 4; ++rg) {
        const int m = mt * 64 + mf * 16 + (lane >> 4) * 4 + rg;
#pragma unroll
        for (int nf = 0; nf < 4; ++nf) {
          const int n = nb * 256 + wn * 64 + nf * 16 + (lane & 15);
          const int bb = n >> 10, ll = n & 1023;
          dst[(bb * COUT + m) * LPIX + ll] = to_bf16(acc[mf][nf][rg]);
        }
      }
  } else {
#pragma unroll
    for (int mf = 0; mf < 4; ++mf)
#pragma unroll
      for (int rg = 0; rg < 4; ++rg) {
        const int m = mt * 64 + mf * 16 + (lane >> 4) * 4 + rg;
        const float bv = bias[m];
#pragma unroll
        for (int nf = 0; nf < 4; ++nf) {
          const int n = nb * 256 + wn * 64 + nf * 16 + (lane & 15);
          const int bb = n >> 10, ll = n & 1023;
          out[(bb * COUT + m) * LPIX + ll] = acc[mf][nf][rg] + bv;
        }
      }
  }
}

__global__ void add_kernel(float* __restrict__ out, const ushort_t* __restrict__ part) {
  const int i = (blockIdx.x * 256 + threadIdx.x) * 8;
  f32x4 a0 = *(const f32x4*)&out[i];
  f32x4 a1 = *(const f32x4*)&out[i + 4];
#pragma unroll
  for (int j = 0; j < KS - 1; ++j) {
    const short8 pv = *(const short8*)&part[(size_t)j * PART_ELEMS + i];
#pragma unroll
    for (int e = 0; e < 4; ++e) {
      a0[e] += from_bf16((ushort_t)pv[e]);
      a1[e] += from_bf16((ushort_t)pv[e + 4]);
    }
  }
  *(f32x4*)&out[i] = a0;
  *(f32x4*)&out[i + 4] = a1;
}

// ---------------- fallback (only if ws too small): direct evaluation -----
__global__ void naive_kernel(const float* __restrict__ x, const float* __restrict__ wb,
                             const float* __restrict__ wsp, const float* __restrict__ cc,
                             float* __restrict__ out) {
  const int idx = blockIdx.x * 256 + threadIdx.x;
  if (idx >= BATCH * COUT * LPIX) return;
  const int l = idx & 1023, o = (idx >> 10) & 127, b = idx >> 17;
  const int h = l >> 5, w = l & 31;
  float acc = 0.f;
  for (int i = 0; i < CIN; ++i)
    for (int kk = 0; kk < 9; ++kk) {
      const int yy = h + kk / 3 - 1, xx = w + kk % 3 - 1;
      const float v = (yy >= 0 && yy < 32 && xx >= 0 && xx < 32)
                          ? x[((b * CIN + i) * 32 + yy) * 32 + xx] : 0.f;
      float ftr[9];
      basis9(v, ftr);
      const int base = (i * COUT + o) * 9 + kk;
      const float* cp = cc + base * 8;
      float dot = 0.f;
#pragma unroll
      for (int f = 0; f < 8; ++f) dot += cp[f] * ftr[f];
      acc += wsp[base] * dot + wb[base] * ftr[8];
    }
  out[idx] = acc;
}

extern "C" void kernel_launch(void* const* d_in, const int* in_sizes, int n_in,
                              void* d_out, int out_size, void* d_ws, size_t ws_size,
                              hipStream_t stream) {
  const float* x  = (const float*)d_in[0];
  const float* wb = (const float*)d_in[1];
  const float* wsp = (const float*)d_in[2];
  const float* cc = (const float*)d_in[3];
  float* out = (float*)d_out;

  if (ws_size < WS_NEED) {
    naive_kernel<<<(BATCH * COUT * LPIX + 255) / 256, 256, 0, stream>>>(x, wb, wsp, cc, out);
    return;
  }

  char* ws = (char*)d_ws;
  ushort_t* feat = (ushort_t*)ws;
  ushort_t* W    = (ushort_t*)(ws + W_OFF);
  float* bias    = (float*)(ws + BIAS_OFF);
  ushort_t* part = (ushort_t*)(ws + PART_OFF);

  prep_kernel<<<FEAT_BLOCKS + WPREP_BLOCKS, 256, 0, stream>>>(x, feat, wb, wsp, cc, W, bias);
  gemm_kernel<<<64 * 2 * KS, 256, 0, stream>>>(feat, W, bias, out, part);
  add_kernel<<<PART_ELEMS / 2048, 256, 0, stream>>>(out, part);
}